// Round 13
// baseline (147.827 us; speedup 1.0000x reference)
//
#include <hip/hip_runtime.h>
#include <hip/hip_bf16.h>
#include <stdint.h>

// ---------------------------------------------------------------------------
// OptimizedMultiHeadAttn: x:[2,2048,1024] f32, attn_w:[3072,1024], attn_b:[3072],
// proj_w:[1024,1024], proj_b:[1024]  ->  out:[2,2048,1024] f32
// Pipeline: cvt3 -> QKV gemm_bt (scatter Q/K/V^T) -> flash attn -> proj gemm_bt
//
// R12 post-mortem: 1024-block oversubscription created a second generation of
// blocks with its own drain tail (72->79us). This round: PAIRED static
// schedule — block b processes tiles (bh, qlow) and (bh, 31-qlow), so every
// block does a constant 33 iteration-units; grid = 512 = exactly 2/CU, all
// blocks co-resident, no tail. Inner tile structure = R12 (refcheck-passed):
// swapped-operand QK/PV, 4-way strided K-split, in-lane softmax, defer-max,
// 4-partial LDS merge. GEMM launch_bounds(256,3) kept.
// ---------------------------------------------------------------------------

typedef __bf16 bf16_t;
typedef __bf16 bf16x8 __attribute__((ext_vector_type(8)));
typedef float f32x4 __attribute__((ext_vector_type(4)));

#define B_SZ 2
#define S_LEN 2048
#define D_MODEL 1024
#define N_HEADS 16
#define D_HEAD 64
#define M_ROWS (B_SZ * S_LEN)          // 4096
#define QKV_N (3 * N_HEADS * D_HEAD)   // 3072

// Q pre-scale: 1/sqrt(64) * log2(e)  (softmax runs in exp2 domain)
#define Q_SCALE 0.1803368801111204f

// workspace layout (bytes); total 48 MiB
#define OFF_XB  (0ull)
#define OFF_WB  (8ull  << 20)
#define OFF_PWB (14ull << 20)
#define OFF_Q   (16ull << 20)
#define OFF_K   (24ull << 20)
#define OFF_VT  (32ull << 20)
#define OFF_AO  (40ull << 20)

__device__ __forceinline__ unsigned short f2bf_u(float f) {
  union { float f; unsigned u; } v; v.f = f;
  unsigned r = v.u + 0x7fffu + ((v.u >> 16) & 1u);  // RNE
  return (unsigned short)(r >> 16);
}
__device__ __forceinline__ bf16_t f2bf(float f) {
  unsigned short u = f2bf_u(f);
  return __builtin_bit_cast(bf16_t, u);
}
// v_cvt_pk_bf16_f32: D[15:0]=bf16(lo), D[31:16]=bf16(hi) (RNE). No builtin.
__device__ __forceinline__ unsigned cvt_pk_bf16(float lo, float hi) {
  unsigned r;
  asm volatile("v_cvt_pk_bf16_f32 %0, %1, %2" : "=v"(r) : "v"(lo), "v"(hi));
  return r;
}

// ---------------------------------------------------------------------------
__global__ void cvt3_f32_bf16(const float* __restrict__ sa, bf16_t* __restrict__ da, int n4a,
                              const float* __restrict__ sb, bf16_t* __restrict__ db, int n4b,
                              const float* __restrict__ sc, bf16_t* __restrict__ dc, int n4c) {
  int i = blockIdx.x * blockDim.x + threadIdx.x;
  const float* s; bf16_t* d; int j = i;
  if (i < n4a) { s = sa; d = da; }
  else if ((j = i - n4a) < n4b) { s = sb; d = db; }
  else if ((j = i - n4a - n4b) < n4c) { s = sc; d = dc; }
  else return;
  float4 f = reinterpret_cast<const float4*>(s)[j];
  ushort4 o;
  o.x = f2bf_u(f.x); o.y = f2bf_u(f.y); o.z = f2bf_u(f.z); o.w = f2bf_u(f.w);
  reinterpret_cast<ushort4*>(d)[j] = o;
}

// ---------------------------------------------------------------------------
// gemm_bt: C[M,N] = A[M,K] * Bt[N,K]^T + bias, 128x128 tile, BK=64, 4 waves.
#define BM 128
#define BN 128
#define BK 64

__device__ __forceinline__ void gload_lds16(const bf16_t* g, bf16_t* l) {
  __builtin_amdgcn_global_load_lds((__attribute__((address_space(1))) void*)g,
                                   (__attribute__((address_space(3))) void*)l,
                                   16, 0, 0);
}

__device__ __forceinline__ bf16x8 lds_frag(const bf16_t* lds, int row, int kchunk) {
  int pos = kchunk ^ (row & 7);
  return *reinterpret_cast<const bf16x8*>(lds + row * BK + pos * 8);
}

template <int EPI>
__global__ __launch_bounds__(256, 3) void gemm_bt(
    const bf16_t* __restrict__ A, const bf16_t* __restrict__ Bt,
    const float* __restrict__ bias,
    float* __restrict__ fout,
    bf16_t* __restrict__ qout, bf16_t* __restrict__ kout,
    bf16_t* __restrict__ vtout,
    int M, int N, int K) {
  __shared__ bf16_t As[BM * BK];
  __shared__ bf16_t Bs[BN * BK];
  const int tid = threadIdx.x;
  const int lane = tid & 63;
  const int wid = tid >> 6;
  const int wr = wid >> 1, wc = wid & 1;
  const int cl = lane & 15, hl = lane >> 4;
  const int m0 = blockIdx.y * BM, n0 = blockIdx.x * BN;

  f32x4 acc[4][4];
  #pragma unroll
  for (int m = 0; m < 4; ++m)
    #pragma unroll
    for (int n = 0; n < 4; ++n)
      acc[m][n] = (f32x4){0.f, 0.f, 0.f, 0.f};

  for (int kt = 0; kt < K; kt += BK) {
    #pragma unroll
    for (int it = 0; it < 4; ++it) {
      int chunk = it * 256 + tid;
      int row = chunk >> 3, cpos = chunk & 7;
      int csrc = cpos ^ (row & 7);
      bf16_t* ldsA = As + (it * 256 + wid * 64) * 8;
      bf16_t* ldsB = Bs + (it * 256 + wid * 64) * 8;
      gload_lds16(A  + (size_t)(m0 + row) * K + kt + csrc * 8, ldsA);
      gload_lds16(Bt + (size_t)(n0 + row) * K + kt + csrc * 8, ldsB);
    }
    __syncthreads();

    bf16x8 af[2][4], bfr[2][4];
    #pragma unroll
    for (int kk = 0; kk < 2; ++kk) {
      #pragma unroll
      for (int m = 0; m < 4; ++m)
        af[kk][m] = lds_frag(As, wr * 64 + m * 16 + cl, kk * 4 + hl);
      #pragma unroll
      for (int n = 0; n < 4; ++n)
        bfr[kk][n] = lds_frag(Bs, wc * 64 + n * 16 + cl, kk * 4 + hl);
    }
    __builtin_amdgcn_s_setprio(1);
    #pragma unroll
    for (int m = 0; m < 4; ++m)
      #pragma unroll
      for (int n = 0; n < 4; ++n) {
        acc[m][n] = __builtin_amdgcn_mfma_f32_16x16x32_bf16(af[0][m], bfr[0][n], acc[m][n], 0, 0, 0);
        acc[m][n] = __builtin_amdgcn_mfma_f32_16x16x32_bf16(af[1][m], bfr[1][n], acc[m][n], 0, 0, 0);
      }
    __builtin_amdgcn_s_setprio(0);
    __syncthreads();
  }

  #pragma unroll
  for (int n = 0; n < 4; ++n) {
    int ng = n0 + wc * 64 + n * 16 + cl;
    float bv = bias[ng];
    if constexpr (EPI == 0) {
      int part = ng >> 10;         // 0=Q 1=K 2=V
      int r = ng & 1023;
      int h = r >> 6, dk = r & 63;
      #pragma unroll
      for (int m = 0; m < 4; ++m)
        #pragma unroll
        for (int j = 0; j < 4; ++j) {
          int mg = m0 + wr * 64 + m * 16 + hl * 4 + j;
          int b = mg >> 11, s = mg & 2047;
          float val = acc[m][n][j] + bv;
          size_t bh = (size_t)(b * N_HEADS + h);
          if (part == 0)
            qout[(bh * S_LEN + s) * D_HEAD + dk] = f2bf(val * Q_SCALE);
          else if (part == 1)
            kout[(bh * S_LEN + s) * D_HEAD + dk] = f2bf(val);
          else
            vtout[(bh * D_HEAD + dk) * S_LEN + s] = f2bf(val);
        }
    } else {
      #pragma unroll
      for (int m = 0; m < 4; ++m)
        #pragma unroll
        for (int j = 0; j < 4; ++j) {
          int mg = m0 + wr * 64 + m * 16 + hl * 4 + j;
          fout[(size_t)mg * N + ng] = acc[m][n][j] + bv;
        }
    }
  }
}

// ---------------------------------------------------------------------------
// Flash attention, causal, exp2 domain, swapped-operand layout.
// PAIRED static schedule: grid = 512 blocks (exactly 2/CU). Block b:
//   bh = b>>4, qlow = b&15; processes tile (bh, qlow) then (bh, 31-qlow)
//   -> constant 33 iteration-units per block, zero drain tail.
// Per tile (64 q-rows): 8 waves; wave w: ks=w&3 (K-split, kt = ks,ks+4,..<=qt),
// wq=w>>2 (row half); rows row0[rf] = qt*64 + wq*32 + rf*16.
// 4-partial merge via LDS (ks=1..3 write, ks=0 combines+stores); extra
// __syncthreads per tile protects plds/mbuf aliasing across tiles.
__global__ __launch_bounds__(512, 2) void attn_fwd(
    const bf16_t* __restrict__ q,    // [B,H,S,DK], pre-scaled by Q_SCALE
    const bf16_t* __restrict__ k,    // [B,H,S,DK]
    const bf16_t* __restrict__ vt,   // [B,H,DK,S]
    bf16_t* __restrict__ ao) {       // [B*S, H*DK]
  const int blk = blockIdx.x;                      // 0..511
  const int bh = blk >> 4;
  const int qlow = blk & 15;
  const int tid = threadIdx.x;
  const int lane = tid & 63, w = tid >> 6;
  const int ks = w & 3, wq = w >> 2;
  const int cl = lane & 15, hl = lane >> 4;
  const bf16_t* qb = q + (size_t)bh * S_LEN * D_HEAD;
  const bf16_t* kb = k + (size_t)bh * S_LEN * D_HEAD;
  const bf16_t* vb = vt + (size_t)bh * D_HEAD * S_LEN;
  const int b = bh >> 4, h = bh & 15;

  // phase 1: per-wave P tiles [8][32 rows][72] bf16 (36864 B)
  // phase 2: merge buffer [3 slots][64 rows][68] f32 (52224 B), barrier-sep.
  __shared__ __align__(16) char smem[52224];
  auto plds = reinterpret_cast<bf16_t(*)[32][72]>(smem);
  auto mbuf = reinterpret_cast<float(*)[68]>(smem);   // [slot*64 + row][68]

  #pragma unroll 1
  for (int tile = 0; tile < 2; ++tile) {
    const int qt = tile ? (31 - qlow) : qlow;
    const int qbase = qt * 64;
    const int row0[2] = { qbase + wq * 32, qbase + wq * 32 + 16 };

    // Q fragments (B-operand): lane (cl,hl) holds Q[row0+cl][hl*8+e]
    bf16x8 qf[2][2];
    #pragma unroll
    for (int rf = 0; rf < 2; ++rf) {
      const bf16_t* qr = qb + (size_t)(row0[rf] + cl) * D_HEAD + hl * 8;
      qf[rf][0] = *reinterpret_cast<const bf16x8*>(qr);
      qf[rf][1] = *reinterpret_cast<const bf16x8*>(qr + 32);
    }

    float mrow[2], lrow[2];
    f32x4 acco[2][4];
    #pragma unroll
    for (int rf = 0; rf < 2; ++rf) {
      mrow[rf] = -1e30f; lrow[rf] = 0.f;
      #pragma unroll
      for (int db = 0; db < 4; ++db) acco[rf][db] = (f32x4){0.f, 0.f, 0.f, 0.f};
    }

    for (int kt = ks; kt <= qt; kt += 4) {
      // K fragments (A-operand): K[kt*64+nb*16+cl][hl*8+e]
      bf16x8 kf[4][2];
      #pragma unroll
      for (int nb = 0; nb < 4; ++nb) {
        const bf16_t* kr = kb + (size_t)(kt * 64 + nb * 16 + cl) * D_HEAD + hl * 8;
        kf[nb][0] = *reinterpret_cast<const bf16x8*>(kr);
        kf[nb][1] = *reinterpret_cast<const bf16x8*>(kr + 32);
      }

      // QK^T swapped: sacc[rf][nb][jj] = S[qrow=row0+cl][kpos=kt*64+nb*16+hl*4+jj]
      f32x4 sacc[2][4];
      __builtin_amdgcn_s_setprio(1);
      #pragma unroll
      for (int rf = 0; rf < 2; ++rf)
        #pragma unroll
        for (int nb = 0; nb < 4; ++nb) {
          f32x4 s = (f32x4){0.f, 0.f, 0.f, 0.f};
          s = __builtin_amdgcn_mfma_f32_16x16x32_bf16(kf[nb][0], qf[rf][0], s, 0, 0, 0);
          s = __builtin_amdgcn_mfma_f32_16x16x32_bf16(kf[nb][1], qf[rf][1], s, 0, 0, 0);
          sacc[rf][nb] = s;
        }
      __builtin_amdgcn_s_setprio(0);

      // V fragments (A-operand of PV)
      bf16x8 vf[4][2];
      #pragma unroll
      for (int db = 0; db < 4; ++db) {
        const bf16_t* vr = vb + (size_t)(db * 16 + cl) * S_LEN + kt * 64 + hl * 8;
        vf[db][0] = *reinterpret_cast<const bf16x8*>(vr);
        vf[db][1] = *reinterpret_cast<const bf16x8*>(vr + 32);
      }

      // softmax: per-lane row state, in-lane reductions + 2 shfl
      #pragma unroll
      for (int rf = 0; rf < 2; ++rf) {
        const int qrow = row0[rf] + cl;
        if (kt == qt) {  // diagonal tile: causal mask
          #pragma unroll
          for (int nb = 0; nb < 4; ++nb)
            #pragma unroll
            for (int jj = 0; jj < 4; ++jj) {
              int kpos = kt * 64 + nb * 16 + hl * 4 + jj;
              if (kpos > qrow) sacc[rf][nb][jj] = -1e30f;
            }
        }
        float tm = sacc[rf][0][0];
        #pragma unroll
        for (int nb = 0; nb < 4; ++nb)
          #pragma unroll
          for (int jj = 0; jj < 4; ++jj)
            tm = fmaxf(tm, sacc[rf][nb][jj]);
        tm = fmaxf(tm, __shfl_xor(tm, 16));
        tm = fmaxf(tm, __shfl_xor(tm, 32));
        // defer-max (T13, THR=8)
        if (__any(tm > mrow[rf] + 8.f)) {
          float mnew = fmaxf(mrow[rf], tm);
          float corr = __builtin_amdgcn_exp2f(mrow[rf] - mnew);
          mrow[rf] = mnew;
          lrow[rf] *= corr;
          #pragma unroll
          for (int db = 0; db < 4; ++db) acco[rf][db] *= corr;
        }
        float rs = 0.f;
        #pragma unroll
        for (int nb = 0; nb < 4; ++nb)
          #pragma unroll
          for (int jj = 0; jj < 4; ++jj) {
            float p = __builtin_amdgcn_exp2f(sacc[rf][nb][jj] - mrow[rf]);
            sacc[rf][nb][jj] = p;
            rs += p;
          }
        rs += __shfl_xor(rs, 16);
        rs += __shfl_xor(rs, 32);
        lrow[rf] += rs;
        // P -> LDS: row=rf*16+cl, col=kpos local; cvt_pk pairs -> one b64 / nb
        #pragma unroll
        for (int nb = 0; nb < 4; ++nb) {
          uint2 u;
          u.x = cvt_pk_bf16(sacc[rf][nb][0], sacc[rf][nb][1]);
          u.y = cvt_pk_bf16(sacc[rf][nb][2], sacc[rf][nb][3]);
          *reinterpret_cast<uint2*>(&plds[w][rf * 16 + cl][nb * 16 + hl * 4]) = u;
        }
      }

      // PV swapped: acco = mfma(V^T, P): D[d=db*16+hl*4+j][qrow=cl]
      __builtin_amdgcn_s_setprio(1);
      #pragma unroll
      for (int rf = 0; rf < 2; ++rf) {
        bf16x8 pf0 = *reinterpret_cast<const bf16x8*>(&plds[w][rf * 16 + cl][hl * 8]);
        bf16x8 pf1 = *reinterpret_cast<const bf16x8*>(&plds[w][rf * 16 + cl][32 + hl * 8]);
        #pragma unroll
        for (int db = 0; db < 4; ++db) {
          acco[rf][db] = __builtin_amdgcn_mfma_f32_16x16x32_bf16(vf[db][0], pf0, acco[rf][db], 0, 0, 0);
          acco[rf][db] = __builtin_amdgcn_mfma_f32_16x16x32_bf16(vf[db][1], pf1, acco[rf][db], 0, 0, 0);
        }
      }
      __builtin_amdgcn_s_setprio(0);
    }

    // 4-partial merge: ks=1..3 write partials; ks=0 combines + stores.
    __syncthreads();
    if (ks != 0) {
      const int slot = ks - 1;
      #pragma unroll
      for (int rf = 0; rf < 2; ++rf) {
        const int r = slot * 64 + wq * 32 + rf * 16 + cl;
        #pragma unroll
        for (int db = 0; db < 4; ++db)
          *reinterpret_cast<f32x4*>(&mbuf[r][db * 16 + hl * 4]) = acco[rf][db];
        if (hl == 0)
          *reinterpret_cast<float2*>(&mbuf[r][64]) = make_float2(mrow[rf], lrow[rf]);
      }
    }
    __syncthreads();
    if (ks == 0) {
      #pragma unroll
      for (int rf = 0; rf < 2; ++rf) {
        const int rbase = wq * 32 + rf * 16 + cl;
        float m2[3], l2[3];
        #pragma unroll
        for (int s = 0; s < 3; ++s) {
          float2 ml = *reinterpret_cast<const float2*>(&mbuf[s * 64 + rbase][64]);
          m2[s] = ml.x; l2[s] = ml.y;
        }
        float m = fmaxf(fmaxf(mrow[rf], m2[0]), fmaxf(m2[1], m2[2]));
        float c0 = __builtin_amdgcn_exp2f(mrow[rf] - m);
        float cc[3];
        float l = lrow[rf] * c0;
        #pragma unroll
        for (int s = 0; s < 3; ++s) {
          cc[s] = __builtin_amdgcn_exp2f(m2[s] - m);
          l += l2[s] * cc[s];
        }
        float linv = 1.f / l;
        const int qrow = row0[rf] + cl;
        #pragma unroll
        for (int db = 0; db < 4; ++db) {
          f32x4 o = acco[rf][db] * c0;
          #pragma unroll
          for (int s = 0; s < 3; ++s) {
            f32x4 po = *reinterpret_cast<const f32x4*>(&mbuf[s * 64 + rbase][db * 16 + hl * 4]);
            o += po * cc[s];
          }
          uint2 u;
          u.x = cvt_pk_bf16(o[0] * linv, o[1] * linv);
          u.y = cvt_pk_bf16(o[2] * linv, o[3] * linv);
          *reinterpret_cast<uint2*>(
              ao + ((size_t)(b * S_LEN) + qrow) * D_MODEL + h * D_HEAD + db * 16 + hl * 4) = u;
        }
      }
    }
    __syncthreads();   // protect smem reuse by next tile
  }
}

// ---------------------------------------------------------------------------
extern "C" void kernel_launch(void* const* d_in, const int* in_sizes, int n_in,
                              void* d_out, int out_size, void* d_ws, size_t ws_size,
                              hipStream_t stream) {
  const float* x      = (const float*)d_in[0];
  const float* attn_w = (const float*)d_in[1];
  const float* attn_b = (const float*)d_in[2];
  const float* proj_w = (const float*)d_in[3];
  const float* proj_b = (const float*)d_in[4];
  float* out = (float*)d_out;
  char* ws = (char*)d_ws;

  bf16_t* xb  = (bf16_t*)(ws + OFF_XB);
  bf16_t* wb  = (bf16_t*)(ws + OFF_WB);
  bf16_t* pwb = (bf16_t*)(ws + OFF_PWB);
  bf16_t* qb  = (bf16_t*)(ws + OFF_Q);
  bf16_t* kb  = (bf16_t*)(ws + OFF_K);
  bf16_t* vtb = (bf16_t*)(ws + OFF_VT);
  bf16_t* aob = (bf16_t*)(ws + OFF_AO);

  const int n4a = M_ROWS * D_MODEL / 4;
  const int n4b = QKV_N * D_MODEL / 4;
  const int n4c = D_MODEL * D_MODEL / 4;
  const int n4 = n4a + n4b + n4c;
  cvt3_f32_bf16<<<(n4 + 255) / 256, 256, 0, stream>>>(x, xb, n4a, attn_w, wb, n4b,
                                                      proj_w, pwb, n4c);

  gemm_bt<0><<<dim3(QKV_N / BN, M_ROWS / BM), 256, 0, stream>>>(
      xb, wb, attn_b, nullptr, qb, kb, vtb, M_ROWS, QKV_N, D_MODEL);

  attn_fwd<<<dim3(512), 512, 0, stream>>>(qb, kb, vtb, aob);

  gemm_bt<1><<<dim3(D_MODEL / BN, M_ROWS / BM), 256, 0, stream>>>(
      aob, pwb, proj_b, out, nullptr, nullptr, nullptr, M_ROWS, D_MODEL, D_MODEL);
}

// Round 14
// 147.683 us; speedup vs baseline: 1.0010x; 1.0010x over previous
//
#include <hip/hip_runtime.h>
#include <hip/hip_bf16.h>
#include <stdint.h>

// ---------------------------------------------------------------------------
// OptimizedMultiHeadAttn: x:[2,2048,1024] f32, attn_w:[3072,1024], attn_b:[3072],
// proj_w:[1024,1024], proj_b:[1024]  ->  out:[2,2048,1024] f32
// Pipeline: cvt3 -> QKV gemm_bt (scatter Q/K/V^T) -> flash attn -> proj gemm_bt
//
// R13 post-mortem: paired schedule balanced perfectly but dur stuck at 79us;
// FETCH_SIZE=78MB @ 1116 GB/s ~= dur -> L2-MISS BOUND. Cause: blk=bh*16+qlow
// round-robins over XCDs so every 4MB XCD-L2 must hold K/V of ALL 32 bh
// (16MB, 4x oversubscribed). This round: XCD-locality mapping bh=(blk&7)*4+
// ((blk>>3)&3), qlow=blk>>5 -> each XCD owns 4 bh = 2MB K/V, L2-resident.
// Paired tiles (qlow, 31-qlow) kept: constant 33 iter-units/block, no tail.
// ---------------------------------------------------------------------------

typedef __bf16 bf16_t;
typedef __bf16 bf16x8 __attribute__((ext_vector_type(8)));
typedef float f32x4 __attribute__((ext_vector_type(4)));

#define B_SZ 2
#define S_LEN 2048
#define D_MODEL 1024
#define N_HEADS 16
#define D_HEAD 64
#define M_ROWS (B_SZ * S_LEN)          // 4096
#define QKV_N (3 * N_HEADS * D_HEAD)   // 3072

// Q pre-scale: 1/sqrt(64) * log2(e)  (softmax runs in exp2 domain)
#define Q_SCALE 0.1803368801111204f

// workspace layout (bytes); total 48 MiB
#define OFF_XB  (0ull)
#define OFF_WB  (8ull  << 20)
#define OFF_PWB (14ull << 20)
#define OFF_Q   (16ull << 20)
#define OFF_K   (24ull << 20)
#define OFF_VT  (32ull << 20)
#define OFF_AO  (40ull << 20)

__device__ __forceinline__ unsigned short f2bf_u(float f) {
  union { float f; unsigned u; } v; v.f = f;
  unsigned r = v.u + 0x7fffu + ((v.u >> 16) & 1u);  // RNE
  return (unsigned short)(r >> 16);
}
__device__ __forceinline__ bf16_t f2bf(float f) {
  unsigned short u = f2bf_u(f);
  return __builtin_bit_cast(bf16_t, u);
}
// v_cvt_pk_bf16_f32: D[15:0]=bf16(lo), D[31:16]=bf16(hi) (RNE). No builtin.
__device__ __forceinline__ unsigned cvt_pk_bf16(float lo, float hi) {
  unsigned r;
  asm volatile("v_cvt_pk_bf16_f32 %0, %1, %2" : "=v"(r) : "v"(lo), "v"(hi));
  return r;
}

// ---------------------------------------------------------------------------
__global__ void cvt3_f32_bf16(const float* __restrict__ sa, bf16_t* __restrict__ da, int n4a,
                              const float* __restrict__ sb, bf16_t* __restrict__ db, int n4b,
                              const float* __restrict__ sc, bf16_t* __restrict__ dc, int n4c) {
  int i = blockIdx.x * blockDim.x + threadIdx.x;
  const float* s; bf16_t* d; int j = i;
  if (i < n4a) { s = sa; d = da; }
  else if ((j = i - n4a) < n4b) { s = sb; d = db; }
  else if ((j = i - n4a - n4b) < n4c) { s = sc; d = dc; }
  else return;
  float4 f = reinterpret_cast<const float4*>(s)[j];
  ushort4 o;
  o.x = f2bf_u(f.x); o.y = f2bf_u(f.y); o.z = f2bf_u(f.z); o.w = f2bf_u(f.w);
  reinterpret_cast<ushort4*>(d)[j] = o;
}

// ---------------------------------------------------------------------------
// gemm_bt: C[M,N] = A[M,K] * Bt[N,K]^T + bias, 128x128 tile, BK=64, 4 waves.
#define BM 128
#define BN 128
#define BK 64

__device__ __forceinline__ void gload_lds16(const bf16_t* g, bf16_t* l) {
  __builtin_amdgcn_global_load_lds((__attribute__((address_space(1))) void*)g,
                                   (__attribute__((address_space(3))) void*)l,
                                   16, 0, 0);
}

__device__ __forceinline__ bf16x8 lds_frag(const bf16_t* lds, int row, int kchunk) {
  int pos = kchunk ^ (row & 7);
  return *reinterpret_cast<const bf16x8*>(lds + row * BK + pos * 8);
}

template <int EPI>
__global__ __launch_bounds__(256, 3) void gemm_bt(
    const bf16_t* __restrict__ A, const bf16_t* __restrict__ Bt,
    const float* __restrict__ bias,
    float* __restrict__ fout,
    bf16_t* __restrict__ qout, bf16_t* __restrict__ kout,
    bf16_t* __restrict__ vtout,
    int M, int N, int K) {
  __shared__ bf16_t As[BM * BK];
  __shared__ bf16_t Bs[BN * BK];
  const int tid = threadIdx.x;
  const int lane = tid & 63;
  const int wid = tid >> 6;
  const int wr = wid >> 1, wc = wid & 1;
  const int cl = lane & 15, hl = lane >> 4;
  const int m0 = blockIdx.y * BM, n0 = blockIdx.x * BN;

  f32x4 acc[4][4];
  #pragma unroll
  for (int m = 0; m < 4; ++m)
    #pragma unroll
    for (int n = 0; n < 4; ++n)
      acc[m][n] = (f32x4){0.f, 0.f, 0.f, 0.f};

  for (int kt = 0; kt < K; kt += BK) {
    #pragma unroll
    for (int it = 0; it < 4; ++it) {
      int chunk = it * 256 + tid;
      int row = chunk >> 3, cpos = chunk & 7;
      int csrc = cpos ^ (row & 7);
      bf16_t* ldsA = As + (it * 256 + wid * 64) * 8;
      bf16_t* ldsB = Bs + (it * 256 + wid * 64) * 8;
      gload_lds16(A  + (size_t)(m0 + row) * K + kt + csrc * 8, ldsA);
      gload_lds16(Bt + (size_t)(n0 + row) * K + kt + csrc * 8, ldsB);
    }
    __syncthreads();

    bf16x8 af[2][4], bfr[2][4];
    #pragma unroll
    for (int kk = 0; kk < 2; ++kk) {
      #pragma unroll
      for (int m = 0; m < 4; ++m)
        af[kk][m] = lds_frag(As, wr * 64 + m * 16 + cl, kk * 4 + hl);
      #pragma unroll
      for (int n = 0; n < 4; ++n)
        bfr[kk][n] = lds_frag(Bs, wc * 64 + n * 16 + cl, kk * 4 + hl);
    }
    __builtin_amdgcn_s_setprio(1);
    #pragma unroll
    for (int m = 0; m < 4; ++m)
      #pragma unroll
      for (int n = 0; n < 4; ++n) {
        acc[m][n] = __builtin_amdgcn_mfma_f32_16x16x32_bf16(af[0][m], bfr[0][n], acc[m][n], 0, 0, 0);
        acc[m][n] = __builtin_amdgcn_mfma_f32_16x16x32_bf16(af[1][m], bfr[1][n], acc[m][n], 0, 0, 0);
      }
    __builtin_amdgcn_s_setprio(0);
    __syncthreads();
  }

  #pragma unroll
  for (int n = 0; n < 4; ++n) {
    int ng = n0 + wc * 64 + n * 16 + cl;
    float bv = bias[ng];
    if constexpr (EPI == 0) {
      int part = ng >> 10;         // 0=Q 1=K 2=V
      int r = ng & 1023;
      int h = r >> 6, dk = r & 63;
      #pragma unroll
      for (int m = 0; m < 4; ++m)
        #pragma unroll
        for (int j = 0; j < 4; ++j) {
          int mg = m0 + wr * 64 + m * 16 + hl * 4 + j;
          int b = mg >> 11, s = mg & 2047;
          float val = acc[m][n][j] + bv;
          size_t bh = (size_t)(b * N_HEADS + h);
          if (part == 0)
            qout[(bh * S_LEN + s) * D_HEAD + dk] = f2bf(val * Q_SCALE);
          else if (part == 1)
            kout[(bh * S_LEN + s) * D_HEAD + dk] = f2bf(val);
          else
            vtout[(bh * D_HEAD + dk) * S_LEN + s] = f2bf(val);
        }
    } else {
      #pragma unroll
      for (int m = 0; m < 4; ++m)
        #pragma unroll
        for (int j = 0; j < 4; ++j) {
          int mg = m0 + wr * 64 + m * 16 + hl * 4 + j;
          fout[(size_t)mg * N + ng] = acc[m][n][j] + bv;
        }
    }
  }
}

// ---------------------------------------------------------------------------
// Flash attention, causal, exp2 domain, swapped-operand layout.
// XCD-LOCAL paired schedule: grid = 512 blocks (exactly 2/CU). With
// consecutive blocks round-robining over the 8 XCDs (blk&7 = XCD):
//   bh  = (blk&7)*4 + ((blk>>3)&3)   -> each XCD serves exactly 4 bh
//   qlow = blk>>5                     -> tiles (bh,qlow) and (bh,31-qlow)
// K/V working set per XCD = 4 bh x 512KB = 2MB <= 4MB L2 (was 16MB, 4x over).
// Per tile (64 q-rows): 8 waves; wave w: ks=w&3 (K-split, kt=ks,ks+4,..<=qt),
// wq=w>>2 (row half); 4-partial LDS merge; constant 33 iter-units/block.
__global__ __launch_bounds__(512, 2) void attn_fwd(
    const bf16_t* __restrict__ q,    // [B,H,S,DK], pre-scaled by Q_SCALE
    const bf16_t* __restrict__ k,    // [B,H,S,DK]
    const bf16_t* __restrict__ vt,   // [B,H,DK,S]
    bf16_t* __restrict__ ao) {       // [B*S, H*DK]
  const int blk = blockIdx.x;                      // 0..511
  const int bh = (blk & 7) * 4 + ((blk >> 3) & 3); // XCD-local head mapping
  const int qlow = blk >> 5;                       // 0..15
  const int tid = threadIdx.x;
  const int lane = tid & 63, w = tid >> 6;
  const int ks = w & 3, wq = w >> 2;
  const int cl = lane & 15, hl = lane >> 4;
  const bf16_t* qb = q + (size_t)bh * S_LEN * D_HEAD;
  const bf16_t* kb = k + (size_t)bh * S_LEN * D_HEAD;
  const bf16_t* vb = vt + (size_t)bh * D_HEAD * S_LEN;
  const int b = bh >> 4, h = bh & 15;

  // phase 1: per-wave P tiles [8][32 rows][72] bf16 (36864 B)
  // phase 2: merge buffer [3 slots][64 rows][68] f32 (52224 B), barrier-sep.
  __shared__ __align__(16) char smem[52224];
  auto plds = reinterpret_cast<bf16_t(*)[32][72]>(smem);
  auto mbuf = reinterpret_cast<float(*)[68]>(smem);   // [slot*64 + row][68]

  #pragma unroll 1
  for (int tile = 0; tile < 2; ++tile) {
    const int qt = tile ? (31 - qlow) : qlow;
    const int qbase = qt * 64;
    const int row0[2] = { qbase + wq * 32, qbase + wq * 32 + 16 };

    // Q fragments (B-operand): lane (cl,hl) holds Q[row0+cl][hl*8+e]
    bf16x8 qf[2][2];
    #pragma unroll
    for (int rf = 0; rf < 2; ++rf) {
      const bf16_t* qr = qb + (size_t)(row0[rf] + cl) * D_HEAD + hl * 8;
      qf[rf][0] = *reinterpret_cast<const bf16x8*>(qr);
      qf[rf][1] = *reinterpret_cast<const bf16x8*>(qr + 32);
    }

    float mrow[2], lrow[2];
    f32x4 acco[2][4];
    #pragma unroll
    for (int rf = 0; rf < 2; ++rf) {
      mrow[rf] = -1e30f; lrow[rf] = 0.f;
      #pragma unroll
      for (int db = 0; db < 4; ++db) acco[rf][db] = (f32x4){0.f, 0.f, 0.f, 0.f};
    }

    for (int kt = ks; kt <= qt; kt += 4) {
      // K fragments (A-operand): K[kt*64+nb*16+cl][hl*8+e]
      bf16x8 kf[4][2];
      #pragma unroll
      for (int nb = 0; nb < 4; ++nb) {
        const bf16_t* kr = kb + (size_t)(kt * 64 + nb * 16 + cl) * D_HEAD + hl * 8;
        kf[nb][0] = *reinterpret_cast<const bf16x8*>(kr);
        kf[nb][1] = *reinterpret_cast<const bf16x8*>(kr + 32);
      }

      // QK^T swapped: sacc[rf][nb][jj] = S[qrow=row0+cl][kpos=kt*64+nb*16+hl*4+jj]
      f32x4 sacc[2][4];
      __builtin_amdgcn_s_setprio(1);
      #pragma unroll
      for (int rf = 0; rf < 2; ++rf)
        #pragma unroll
        for (int nb = 0; nb < 4; ++nb) {
          f32x4 s = (f32x4){0.f, 0.f, 0.f, 0.f};
          s = __builtin_amdgcn_mfma_f32_16x16x32_bf16(kf[nb][0], qf[rf][0], s, 0, 0, 0);
          s = __builtin_amdgcn_mfma_f32_16x16x32_bf16(kf[nb][1], qf[rf][1], s, 0, 0, 0);
          sacc[rf][nb] = s;
        }
      __builtin_amdgcn_s_setprio(0);

      // V fragments (A-operand of PV)
      bf16x8 vf[4][2];
      #pragma unroll
      for (int db = 0; db < 4; ++db) {
        const bf16_t* vr = vb + (size_t)(db * 16 + cl) * S_LEN + kt * 64 + hl * 8;
        vf[db][0] = *reinterpret_cast<const bf16x8*>(vr);
        vf[db][1] = *reinterpret_cast<const bf16x8*>(vr + 32);
      }

      // softmax: per-lane row state, in-lane reductions + 2 shfl
      #pragma unroll
      for (int rf = 0; rf < 2; ++rf) {
        const int qrow = row0[rf] + cl;
        if (kt == qt) {  // diagonal tile: causal mask
          #pragma unroll
          for (int nb = 0; nb < 4; ++nb)
            #pragma unroll
            for (int jj = 0; jj < 4; ++jj) {
              int kpos = kt * 64 + nb * 16 + hl * 4 + jj;
              if (kpos > qrow) sacc[rf][nb][jj] = -1e30f;
            }
        }
        float tm = sacc[rf][0][0];
        #pragma unroll
        for (int nb = 0; nb < 4; ++nb)
          #pragma unroll
          for (int jj = 0; jj < 4; ++jj)
            tm = fmaxf(tm, sacc[rf][nb][jj]);
        tm = fmaxf(tm, __shfl_xor(tm, 16));
        tm = fmaxf(tm, __shfl_xor(tm, 32));
        // defer-max (T13, THR=8)
        if (__any(tm > mrow[rf] + 8.f)) {
          float mnew = fmaxf(mrow[rf], tm);
          float corr = __builtin_amdgcn_exp2f(mrow[rf] - mnew);
          mrow[rf] = mnew;
          lrow[rf] *= corr;
          #pragma unroll
          for (int db = 0; db < 4; ++db) acco[rf][db] *= corr;
        }
        float rs = 0.f;
        #pragma unroll
        for (int nb = 0; nb < 4; ++nb)
          #pragma unroll
          for (int jj = 0; jj < 4; ++jj) {
            float p = __builtin_amdgcn_exp2f(sacc[rf][nb][jj] - mrow[rf]);
            sacc[rf][nb][jj] = p;
            rs += p;
          }
        rs += __shfl_xor(rs, 16);
        rs += __shfl_xor(rs, 32);
        lrow[rf] += rs;
        // P -> LDS: row=rf*16+cl, col=kpos local; cvt_pk pairs -> one b64 / nb
        #pragma unroll
        for (int nb = 0; nb < 4; ++nb) {
          uint2 u;
          u.x = cvt_pk_bf16(sacc[rf][nb][0], sacc[rf][nb][1]);
          u.y = cvt_pk_bf16(sacc[rf][nb][2], sacc[rf][nb][3]);
          *reinterpret_cast<uint2*>(&plds[w][rf * 16 + cl][nb * 16 + hl * 4]) = u;
        }
      }

      // PV swapped: acco = mfma(V^T, P): D[d=db*16+hl*4+j][qrow=cl]
      __builtin_amdgcn_s_setprio(1);
      #pragma unroll
      for (int rf = 0; rf < 2; ++rf) {
        bf16x8 pf0 = *reinterpret_cast<const bf16x8*>(&plds[w][rf * 16 + cl][hl * 8]);
        bf16x8 pf1 = *reinterpret_cast<const bf16x8*>(&plds[w][rf * 16 + cl][32 + hl * 8]);
        #pragma unroll
        for (int db = 0; db < 4; ++db) {
          acco[rf][db] = __builtin_amdgcn_mfma_f32_16x16x32_bf16(vf[db][0], pf0, acco[rf][db], 0, 0, 0);
          acco[rf][db] = __builtin_amdgcn_mfma_f32_16x16x32_bf16(vf[db][1], pf1, acco[rf][db], 0, 0, 0);
        }
      }
      __builtin_amdgcn_s_setprio(0);
    }

    // 4-partial merge: ks=1..3 write partials; ks=0 combines + stores.
    __syncthreads();
    if (ks != 0) {
      const int slot = ks - 1;
      #pragma unroll
      for (int rf = 0; rf < 2; ++rf) {
        const int r = slot * 64 + wq * 32 + rf * 16 + cl;
        #pragma unroll
        for (int db = 0; db < 4; ++db)
          *reinterpret_cast<f32x4*>(&mbuf[r][db * 16 + hl * 4]) = acco[rf][db];
        if (hl == 0)
          *reinterpret_cast<float2*>(&mbuf[r][64]) = make_float2(mrow[rf], lrow[rf]);
      }
    }
    __syncthreads();
    if (ks == 0) {
      #pragma unroll
      for (int rf = 0; rf < 2; ++rf) {
        const int rbase = wq * 32 + rf * 16 + cl;
        float m2[3], l2[3];
        #pragma unroll
        for (int s = 0; s < 3; ++s) {
          float2 ml = *reinterpret_cast<const float2*>(&mbuf[s * 64 + rbase][64]);
          m2[s] = ml.x; l2[s] = ml.y;
        }
        float m = fmaxf(fmaxf(mrow[rf], m2[0]), fmaxf(m2[1], m2[2]));
        float c0 = __builtin_amdgcn_exp2f(mrow[rf] - m);
        float cc[3];
        float l = lrow[rf] * c0;
        #pragma unroll
        for (int s = 0; s < 3; ++s) {
          cc[s] = __builtin_amdgcn_exp2f(m2[s] - m);
          l += l2[s] * cc[s];
        }
        float linv = 1.f / l;
        const int qrow = row0[rf] + cl;
        #pragma unroll
        for (int db = 0; db < 4; ++db) {
          f32x4 o = acco[rf][db] * c0;
          #pragma unroll
          for (int s = 0; s < 3; ++s) {
            f32x4 po = *reinterpret_cast<const f32x4*>(&mbuf[s * 64 + rbase][db * 16 + hl * 4]);
            o += po * cc[s];
          }
          uint2 u;
          u.x = cvt_pk_bf16(o[0] * linv, o[1] * linv);
          u.y = cvt_pk_bf16(o[2] * linv, o[3] * linv);
          *reinterpret_cast<uint2*>(
              ao + ((size_t)(b * S_LEN) + qrow) * D_MODEL + h * D_HEAD + db * 16 + hl * 4) = u;
        }
      }
    }
    __syncthreads();   // protect smem reuse by next tile
  }
}

// ---------------------------------------------------------------------------
extern "C" void kernel_launch(void* const* d_in, const int* in_sizes, int n_in,
                              void* d_out, int out_size, void* d_ws, size_t ws_size,
                              hipStream_t stream) {
  const float* x      = (const float*)d_in[0];
  const float* attn_w = (const float*)d_in[1];
  const float* attn_b = (const float*)d_in[2];
  const float* proj_w = (const float*)d_in[3];
  const float* proj_b = (const float*)d_in[4];
  float* out = (float*)d_out;
  char* ws = (char*)d_ws;

  bf16_t* xb  = (bf16_t*)(ws + OFF_XB);
  bf16_t* wb  = (bf16_t*)(ws + OFF_WB);
  bf16_t* pwb = (bf16_t*)(ws + OFF_PWB);
  bf16_t* qb  = (bf16_t*)(ws + OFF_Q);
  bf16_t* kb  = (bf16_t*)(ws + OFF_K);
  bf16_t* vtb = (bf16_t*)(ws + OFF_VT);
  bf16_t* aob = (bf16_t*)(ws + OFF_AO);

  const int n4a = M_ROWS * D_MODEL / 4;
  const int n4b = QKV_N * D_MODEL / 4;
  const int n4c = D_MODEL * D_MODEL / 4;
  const int n4 = n4a + n4b + n4c;
  cvt3_f32_bf16<<<(n4 + 255) / 256, 256, 0, stream>>>(x, xb, n4a, attn_w, wb, n4b,
                                                      proj_w, pwb, n4c);

  gemm_bt<0><<<dim3(QKV_N / BN, M_ROWS / BM), 256, 0, stream>>>(
      xb, wb, attn_b, nullptr, qb, kb, vtb, M_ROWS, QKV_N, D_MODEL);

  attn_fwd<<<dim3(512), 512, 0, stream>>>(qb, kb, vtb, aob);

  gemm_bt<1><<<dim3(D_MODEL / BN, M_ROWS / BM), 256, 0, stream>>>(
      aob, pwb, proj_b, out, nullptr, nullptr, nullptr, M_ROWS, D_MODEL, D_MODEL);
}

// Round 15
// 118.303 us; speedup vs baseline: 1.2496x; 1.2483x over previous
//
#include <hip/hip_runtime.h>
#include <hip/hip_bf16.h>
#include <stdint.h>

// ---------------------------------------------------------------------------
// OptimizedMultiHeadAttn: x:[2,2048,1024] f32, attn_w:[3072,1024], attn_b:[3072],
// proj_w:[1024,1024], proj_b:[1024]  ->  out:[2,2048,1024] f32
// Pipeline: cvt3 -> QKV gemm_bt (scatter Q/K/V^T) -> flash attn -> proj gemm_bt
//
// R14 post-mortem: XCD mapping fixed FETCH (78->12MB) but dur stuck at 79us
// across 3 structurally different rounds. Shared invariant: each wave loads
// its own K/V fragments from global = 16KB/wave-iteration = 540MB through the
// per-CU L1/TA path = 11 B/cy/CU (the measured VMEM streaming ceiling).
// This round: K/V staged ONCE per block into LDS (global_load_lds, double
// buffered, XOR-swizzled source + swizzled ds_read_b128 per rule #21) ->
// 8x VMEM cut. 128-row tiles, 8 waves x 16 rows, serial kt (no ks-split, no
// merge). Paired tiles (qp,15-qp): constant 34 units/block; 256 blocks=1/CU,
// zero tail; XCD-local bh mapping kept.
// ---------------------------------------------------------------------------

typedef __bf16 bf16_t;
typedef __bf16 bf16x8 __attribute__((ext_vector_type(8)));
typedef float f32x4 __attribute__((ext_vector_type(4)));

#define B_SZ 2
#define S_LEN 2048
#define D_MODEL 1024
#define N_HEADS 16
#define D_HEAD 64
#define M_ROWS (B_SZ * S_LEN)          // 4096
#define QKV_N (3 * N_HEADS * D_HEAD)   // 3072

// Q pre-scale: 1/sqrt(64) * log2(e)  (softmax runs in exp2 domain)
#define Q_SCALE 0.1803368801111204f

// workspace layout (bytes); total 48 MiB
#define OFF_XB  (0ull)
#define OFF_WB  (8ull  << 20)
#define OFF_PWB (14ull << 20)
#define OFF_Q   (16ull << 20)
#define OFF_K   (24ull << 20)
#define OFF_VT  (32ull << 20)
#define OFF_AO  (40ull << 20)

__device__ __forceinline__ unsigned short f2bf_u(float f) {
  union { float f; unsigned u; } v; v.f = f;
  unsigned r = v.u + 0x7fffu + ((v.u >> 16) & 1u);  // RNE
  return (unsigned short)(r >> 16);
}
__device__ __forceinline__ bf16_t f2bf(float f) {
  unsigned short u = f2bf_u(f);
  return __builtin_bit_cast(bf16_t, u);
}
// v_cvt_pk_bf16_f32: D[15:0]=bf16(lo), D[31:16]=bf16(hi) (RNE). No builtin.
__device__ __forceinline__ unsigned cvt_pk_bf16(float lo, float hi) {
  unsigned r;
  asm volatile("v_cvt_pk_bf16_f32 %0, %1, %2" : "=v"(r) : "v"(lo), "v"(hi));
  return r;
}

// ---------------------------------------------------------------------------
__global__ void cvt3_f32_bf16(const float* __restrict__ sa, bf16_t* __restrict__ da, int n4a,
                              const float* __restrict__ sb, bf16_t* __restrict__ db, int n4b,
                              const float* __restrict__ sc, bf16_t* __restrict__ dc, int n4c) {
  int i = blockIdx.x * blockDim.x + threadIdx.x;
  const float* s; bf16_t* d; int j = i;
  if (i < n4a) { s = sa; d = da; }
  else if ((j = i - n4a) < n4b) { s = sb; d = db; }
  else if ((j = i - n4a - n4b) < n4c) { s = sc; d = dc; }
  else return;
  float4 f = reinterpret_cast<const float4*>(s)[j];
  ushort4 o;
  o.x = f2bf_u(f.x); o.y = f2bf_u(f.y); o.z = f2bf_u(f.z); o.w = f2bf_u(f.w);
  reinterpret_cast<ushort4*>(d)[j] = o;
}

// ---------------------------------------------------------------------------
// gemm_bt: C[M,N] = A[M,K] * Bt[N,K]^T + bias, 128x128 tile, BK=64, 4 waves.
#define BM 128
#define BN 128
#define BK 64

__device__ __forceinline__ void gload_lds16(const bf16_t* g, bf16_t* l) {
  __builtin_amdgcn_global_load_lds((__attribute__((address_space(1))) void*)g,
                                   (__attribute__((address_space(3))) void*)l,
                                   16, 0, 0);
}

__device__ __forceinline__ bf16x8 lds_frag(const bf16_t* lds, int row, int kchunk) {
  int pos = kchunk ^ (row & 7);
  return *reinterpret_cast<const bf16x8*>(lds + row * BK + pos * 8);
}

template <int EPI>
__global__ __launch_bounds__(256, 3) void gemm_bt(
    const bf16_t* __restrict__ A, const bf16_t* __restrict__ Bt,
    const float* __restrict__ bias,
    float* __restrict__ fout,
    bf16_t* __restrict__ qout, bf16_t* __restrict__ kout,
    bf16_t* __restrict__ vtout,
    int M, int N, int K) {
  __shared__ bf16_t As[BM * BK];
  __shared__ bf16_t Bs[BN * BK];
  const int tid = threadIdx.x;
  const int lane = tid & 63;
  const int wid = tid >> 6;
  const int wr = wid >> 1, wc = wid & 1;
  const int cl = lane & 15, hl = lane >> 4;
  const int m0 = blockIdx.y * BM, n0 = blockIdx.x * BN;

  f32x4 acc[4][4];
  #pragma unroll
  for (int m = 0; m < 4; ++m)
    #pragma unroll
    for (int n = 0; n < 4; ++n)
      acc[m][n] = (f32x4){0.f, 0.f, 0.f, 0.f};

  for (int kt = 0; kt < K; kt += BK) {
    #pragma unroll
    for (int it = 0; it < 4; ++it) {
      int chunk = it * 256 + tid;
      int row = chunk >> 3, cpos = chunk & 7;
      int csrc = cpos ^ (row & 7);
      bf16_t* ldsA = As + (it * 256 + wid * 64) * 8;
      bf16_t* ldsB = Bs + (it * 256 + wid * 64) * 8;
      gload_lds16(A  + (size_t)(m0 + row) * K + kt + csrc * 8, ldsA);
      gload_lds16(Bt + (size_t)(n0 + row) * K + kt + csrc * 8, ldsB);
    }
    __syncthreads();

    bf16x8 af[2][4], bfr[2][4];
    #pragma unroll
    for (int kk = 0; kk < 2; ++kk) {
      #pragma unroll
      for (int m = 0; m < 4; ++m)
        af[kk][m] = lds_frag(As, wr * 64 + m * 16 + cl, kk * 4 + hl);
      #pragma unroll
      for (int n = 0; n < 4; ++n)
        bfr[kk][n] = lds_frag(Bs, wc * 64 + n * 16 + cl, kk * 4 + hl);
    }
    __builtin_amdgcn_s_setprio(1);
    #pragma unroll
    for (int m = 0; m < 4; ++m)
      #pragma unroll
      for (int n = 0; n < 4; ++n) {
        acc[m][n] = __builtin_amdgcn_mfma_f32_16x16x32_bf16(af[0][m], bfr[0][n], acc[m][n], 0, 0, 0);
        acc[m][n] = __builtin_amdgcn_mfma_f32_16x16x32_bf16(af[1][m], bfr[1][n], acc[m][n], 0, 0, 0);
      }
    __builtin_amdgcn_s_setprio(0);
    __syncthreads();
  }

  #pragma unroll
  for (int n = 0; n < 4; ++n) {
    int ng = n0 + wc * 64 + n * 16 + cl;
    float bv = bias[ng];
    if constexpr (EPI == 0) {
      int part = ng >> 10;         // 0=Q 1=K 2=V
      int r = ng & 1023;
      int h = r >> 6, dk = r & 63;
      #pragma unroll
      for (int m = 0; m < 4; ++m)
        #pragma unroll
        for (int j = 0; j < 4; ++j) {
          int mg = m0 + wr * 64 + m * 16 + hl * 4 + j;
          int b = mg >> 11, s = mg & 2047;
          float val = acc[m][n][j] + bv;
          size_t bh = (size_t)(b * N_HEADS + h);
          if (part == 0)
            qout[(bh * S_LEN + s) * D_HEAD + dk] = f2bf(val * Q_SCALE);
          else if (part == 1)
            kout[(bh * S_LEN + s) * D_HEAD + dk] = f2bf(val);
          else
            vtout[(bh * D_HEAD + dk) * S_LEN + s] = f2bf(val);
        }
    } else {
      #pragma unroll
      for (int m = 0; m < 4; ++m)
        #pragma unroll
        for (int j = 0; j < 4; ++j) {
          int mg = m0 + wr * 64 + m * 16 + hl * 4 + j;
          fout[(size_t)mg * N + ng] = acc[m][n][j] + bv;
        }
    }
  }
}

// ---------------------------------------------------------------------------
// Flash attention, causal, exp2 domain, swapped-operand layout, LDS-staged K/V.
// Grid = 256 blocks (1/CU, zero tail). blk&7 = XCD:
//   bh = (blk&7)*4 + ((blk>>3)&3)  (4 heads/XCD -> K/V L2-resident)
//   qp = blk>>5 in 0..7; block processes 128-row tiles qt=qp and qt=15-qp
//   -> constant 34 iteration-units per block.
// Per tile: 8 waves x 16 q-rows; serial kt in 0..2qt+1; K/V tile (16KB)
// staged once per iteration via global_load_lds (double-buffered, source
// XOR-swizzled so swizzled ds_read_b128 fragment reads are conflict-free).
__global__ __launch_bounds__(512, 1) void attn_fwd(
    const bf16_t* __restrict__ q,    // [B,H,S,DK], pre-scaled by Q_SCALE
    const bf16_t* __restrict__ k,    // [B,H,S,DK]
    const bf16_t* __restrict__ vt,   // [B,H,DK,S]
    bf16_t* __restrict__ ao) {       // [B*S, H*DK]
  const int blk = blockIdx.x;                      // 0..255
  const int bh = (blk & 7) * 4 + ((blk >> 3) & 3); // XCD-local head mapping
  const int qp = blk >> 5;                         // 0..7
  const int tid = threadIdx.x;
  const int lane = tid & 63, w = tid >> 6;
  const int cl = lane & 15, hl = lane >> 4;
  const bf16_t* qb = q + (size_t)bh * S_LEN * D_HEAD;
  const bf16_t* kb = k + (size_t)bh * S_LEN * D_HEAD;
  const bf16_t* vb = vt + (size_t)bh * D_HEAD * S_LEN;
  const int b = bh >> 4, h = bh & 15;

  // K/V double buffer: [buf][K=0/V=1][64 rows x 64 elems] bf16 (32 KB)
  // P tiles: per-wave [16 rows][72] bf16 (18 KB). Total 50 KB.
  __shared__ bf16_t kvbuf[2][2][4096];
  __shared__ bf16_t plds[8][16][72];

  // staging: thread t owns 16B chunk t of K and of V. LDS dest linear
  // (chunk t at elems t*8, wave-uniform base + lane*16); global source
  // column pre-swizzled: scc = (t&7) ^ (row&7)  (rule #21).
  const int srow = tid >> 3;               // 0..63
  const int scc = (tid & 7) ^ (srow & 7);  // swizzled 8-elem chunk index
  const int sw = cl & 7;                   // read-side swizzle key

  #pragma unroll 1
  for (int tile = 0; tile < 2; ++tile) {
    const int qt = tile ? (15 - qp) : qp;            // 0..15 (128-row tiles)
    const int row0 = qt * 128 + w * 16;
    const int ktb = 2 * qt + 1;                      // last K-tile index

    // Q fragments (B-operand): lane (cl,hl) holds Q[row0+cl][hl*8+e]
    const bf16_t* qr = qb + (size_t)(row0 + cl) * D_HEAD + hl * 8;
    bf16x8 qf0 = *reinterpret_cast<const bf16x8*>(qr);
    bf16x8 qf1 = *reinterpret_cast<const bf16x8*>(qr + 32);

    float mrow = -1e30f, lrow = 0.f;
    f32x4 acco[4];
    #pragma unroll
    for (int db = 0; db < 4; ++db) acco[db] = (f32x4){0.f, 0.f, 0.f, 0.f};

    // prologue: stage kt=0 into buf 0
    gload_lds16(kb + (size_t)(0 * 64 + srow) * D_HEAD + scc * 8, &kvbuf[0][0][w << 9]);
    gload_lds16(vb + (size_t)srow * S_LEN + 0 * 64 + scc * 8,    &kvbuf[0][1][w << 9]);
    __syncthreads();

    int cur = 0;
    for (int kt = 0; kt <= ktb; ++kt) {
      // stage next K/V tile into the other buffer (latency hides under compute)
      if (kt < ktb) {
        gload_lds16(kb + (size_t)((kt + 1) * 64 + srow) * D_HEAD + scc * 8,
                    &kvbuf[cur ^ 1][0][w << 9]);
        gload_lds16(vb + (size_t)srow * S_LEN + (kt + 1) * 64 + scc * 8,
                    &kvbuf[cur ^ 1][1][w << 9]);
      }

      const bool act = (kt * 64) <= (row0 + 15);
      if (act) {
        const bf16_t* kB = kvbuf[cur][0];
        const bf16_t* vB = kvbuf[cur][1];
        // K fragments (A-operand): K[kt*64+nb*16+cl][hl*8+e], swizzled read
        bf16x8 kf[4][2], vf[4][2];
        #pragma unroll
        for (int nb = 0; nb < 4; ++nb) {
          const bf16_t* kr = kB + (nb * 16 + cl) * 64;
          kf[nb][0] = *reinterpret_cast<const bf16x8*>(kr + ((hl ^ sw) << 3));
          kf[nb][1] = *reinterpret_cast<const bf16x8*>(kr + (((hl + 4) ^ sw) << 3));
        }
        #pragma unroll
        for (int db = 0; db < 4; ++db) {
          const bf16_t* vr = vB + (db * 16 + cl) * 64;
          vf[db][0] = *reinterpret_cast<const bf16x8*>(vr + ((hl ^ sw) << 3));
          vf[db][1] = *reinterpret_cast<const bf16x8*>(vr + (((hl + 4) ^ sw) << 3));
        }

        // QK^T swapped: sacc[nb][jj] = S[qrow=row0+cl][kpos=kt*64+nb*16+hl*4+jj]
        f32x4 sacc[4];
        __builtin_amdgcn_s_setprio(1);
        #pragma unroll
        for (int nb = 0; nb < 4; ++nb) {
          f32x4 s = (f32x4){0.f, 0.f, 0.f, 0.f};
          s = __builtin_amdgcn_mfma_f32_16x16x32_bf16(kf[nb][0], qf0, s, 0, 0, 0);
          s = __builtin_amdgcn_mfma_f32_16x16x32_bf16(kf[nb][1], qf1, s, 0, 0, 0);
          sacc[nb] = s;
        }
        __builtin_amdgcn_s_setprio(0);

        // softmax: per-lane row state, in-lane reductions + 2 shfl
        const int qrow = row0 + cl;
        if (kt * 64 + 63 > qrow) {  // diagonal overlap: causal mask
          #pragma unroll
          for (int nb = 0; nb < 4; ++nb)
            #pragma unroll
            for (int jj = 0; jj < 4; ++jj) {
              int kpos = kt * 64 + nb * 16 + hl * 4 + jj;
              if (kpos > qrow) sacc[nb][jj] = -1e30f;
            }
        }
        float tm = sacc[0][0];
        #pragma unroll
        for (int nb = 0; nb < 4; ++nb)
          #pragma unroll
          for (int jj = 0; jj < 4; ++jj)
            tm = fmaxf(tm, sacc[nb][jj]);
        tm = fmaxf(tm, __shfl_xor(tm, 16));
        tm = fmaxf(tm, __shfl_xor(tm, 32));
        // defer-max (T13, THR=8)
        if (__any(tm > mrow + 8.f)) {
          float mnew = fmaxf(mrow, tm);
          float corr = __builtin_amdgcn_exp2f(mrow - mnew);
          mrow = mnew;
          lrow *= corr;
          #pragma unroll
          for (int db = 0; db < 4; ++db) acco[db] *= corr;
        }
        float rs = 0.f;
        #pragma unroll
        for (int nb = 0; nb < 4; ++nb)
          #pragma unroll
          for (int jj = 0; jj < 4; ++jj) {
            float p = __builtin_amdgcn_exp2f(sacc[nb][jj] - mrow);
            sacc[nb][jj] = p;
            rs += p;
          }
        rs += __shfl_xor(rs, 16);
        rs += __shfl_xor(rs, 32);
        lrow += rs;
        // P -> LDS: row=cl (qrow), col=kpos local; cvt_pk pairs -> one b64/nb
        #pragma unroll
        for (int nb = 0; nb < 4; ++nb) {
          uint2 u;
          u.x = cvt_pk_bf16(sacc[nb][0], sacc[nb][1]);
          u.y = cvt_pk_bf16(sacc[nb][2], sacc[nb][3]);
          *reinterpret_cast<uint2*>(&plds[w][cl][nb * 16 + hl * 4]) = u;
        }

        // PV swapped: acco = mfma(V^T, P): D[d=db*16+hl*4+j][qrow=cl]
        bf16x8 pf0 = *reinterpret_cast<const bf16x8*>(&plds[w][cl][hl * 8]);
        bf16x8 pf1 = *reinterpret_cast<const bf16x8*>(&plds[w][cl][32 + hl * 8]);
        __builtin_amdgcn_s_setprio(1);
        #pragma unroll
        for (int db = 0; db < 4; ++db) {
          acco[db] = __builtin_amdgcn_mfma_f32_16x16x32_bf16(vf[db][0], pf0, acco[db], 0, 0, 0);
          acco[db] = __builtin_amdgcn_mfma_f32_16x16x32_bf16(vf[db][1], pf1, acco[db], 0, 0, 0);
        }
        __builtin_amdgcn_s_setprio(0);
      }

      __syncthreads();   // next buffer staged (vmcnt drained) + buf[cur] reads done
      cur ^= 1;
    }

    // output: O[qrow][d] / lrow
    {
      float linv = 1.f / lrow;
      const int qrow = row0 + cl;
      #pragma unroll
      for (int db = 0; db < 4; ++db) {
        uint2 u;
        u.x = cvt_pk_bf16(acco[db][0] * linv, acco[db][1] * linv);
        u.y = cvt_pk_bf16(acco[db][2] * linv, acco[db][3] * linv);
        *reinterpret_cast<uint2*>(
            ao + ((size_t)(b * S_LEN) + qrow) * D_MODEL + h * D_HEAD + db * 16 + hl * 4) = u;
      }
    }
    __syncthreads();   // all reads of kvbuf done before next tile restages buf0
  }
}

// ---------------------------------------------------------------------------
extern "C" void kernel_launch(void* const* d_in, const int* in_sizes, int n_in,
                              void* d_out, int out_size, void* d_ws, size_t ws_size,
                              hipStream_t stream) {
  const float* x      = (const float*)d_in[0];
  const float* attn_w = (const float*)d_in[1];
  const float* attn_b = (const float*)d_in[2];
  const float* proj_w = (const float*)d_in[3];
  const float* proj_b = (const float*)d_in[4];
  float* out = (float*)d_out;
  char* ws = (char*)d_ws;

  bf16_t* xb  = (bf16_t*)(ws + OFF_XB);
  bf16_t* wb  = (bf16_t*)(ws + OFF_WB);
  bf16_t* pwb = (bf16_t*)(ws + OFF_PWB);
  bf16_t* qb  = (bf16_t*)(ws + OFF_Q);
  bf16_t* kb  = (bf16_t*)(ws + OFF_K);
  bf16_t* vtb = (bf16_t*)(ws + OFF_VT);
  bf16_t* aob = (bf16_t*)(ws + OFF_AO);

  const int n4a = M_ROWS * D_MODEL / 4;
  const int n4b = QKV_N * D_MODEL / 4;
  const int n4c = D_MODEL * D_MODEL / 4;
  const int n4 = n4a + n4b + n4c;
  cvt3_f32_bf16<<<(n4 + 255) / 256, 256, 0, stream>>>(x, xb, n4a, attn_w, wb, n4b,
                                                      proj_w, pwb, n4c);

  gemm_bt<0><<<dim3(QKV_N / BN, M_ROWS / BM), 256, 0, stream>>>(
      xb, wb, attn_b, nullptr, qb, kb, vtb, M_ROWS, QKV_N, D_MODEL);

  attn_fwd<<<dim3(256), 512, 0, stream>>>(qb, kb, vtb, aob);

  gemm_bt<1><<<dim3(D_MODEL / BN, M_ROWS / BM), 256, 0, stream>>>(
      aob, pwb, proj_b, out, nullptr, nullptr, nullptr, M_ROWS, D_MODEL, D_MODEL);
}